// Round 6
// baseline (330.428 us; speedup 1.0000x reference)
//
#include <hip/hip_runtime.h>
#include <hip/hip_bf16.h>

// B=4, N=2048, D_MODEL=512, H=4, DK=64, DV=128. fp32 in/out, bf16 MFMA.
// Softmax over BATCH axis (4 values) -> in-register per lane.
// R6 (bisect after R5's all-zero failure): reverted global_load_lds staging
// and pk-bf16 atomics (the two unverifiable R5 subsystems). Kept: fused QKV
// GEMM, Qp/Kp/Vp fragment-packed epilogues, R4-proven VALU staging.
// New epilogue: per-chunk bf16 partial buffers (plain stores, no atomics,
// no memset) + in-place reduce (P0 becomes AO). Workspace 48.5MB via overlay.

typedef __attribute__((ext_vector_type(8))) short short8;   // 8 x bf16
typedef __attribute__((ext_vector_type(4))) float floatx4;  // MFMA 16x16 acc
typedef unsigned short u16;
typedef unsigned int u32;

#define MFMA16(a, b, c) __builtin_amdgcn_mfma_f32_16x16x32_bf16((a), (b), (c), 0, 0, 0)

__device__ __forceinline__ u16 f2bf(float f) {
    union { float f; unsigned u; } v; v.f = f;
    unsigned r = v.u + 0x7fffu + ((v.u >> 16) & 1u);  // RNE
    return (u16)(r >> 16);
}

__device__ __forceinline__ float bf2f(u16 b) {
    union { unsigned u; float f; } v; v.u = ((u32)b) << 16;
    return v.f;
}

__device__ __forceinline__ u32 pk2bf(float a, float b) {
#if __has_builtin(__builtin_amdgcn_cvt_pk_bf16_f32)
    typedef __attribute__((ext_vector_type(2))) __bf16 bf16x2;
    union { bf16x2 v; u32 u; } c;
    c.v = __builtin_amdgcn_cvt_pk_bf16_f32(a, b);
    return c.u;
#else
    return (u32)f2bf(a) | ((u32)f2bf(b) << 16);
#endif
}

__device__ __forceinline__ float ex2(float x) {
#if __has_builtin(__builtin_amdgcn_exp2f)
    return __builtin_amdgcn_exp2f(x);
#else
    return exp2f(x);
#endif
}

// ---------------- cast fp32 -> bf16 (X) ----------------
__global__ __launch_bounds__(256) void cast_x_kernel(const float* __restrict__ x,
                                                     u16* __restrict__ xb) {
    int i = blockIdx.x * 256 + threadIdx.x;  // 1,048,576 float4 groups exactly
    float4 v = ((const float4*)x)[i];
    ushort4 o;
    o.x = f2bf(v.x); o.y = f2bf(v.y); o.z = f2bf(v.z); o.w = f2bf(v.w);
    ((ushort4*)xb)[i] = o;
}

// ---- weights: fp32 [K][N] -> bf16 transposed [N][K]; [Wq|Wk|Wv] fused ----
// Q columns pre-scaled by 0.125*log2(e) so S arrives in log2 domain.
__global__ __launch_bounds__(256) void prep_w_kernel(
    const float* __restrict__ Wq, const float* __restrict__ Wk,
    const float* __restrict__ Wv, const float* __restrict__ Wo,
    u16* __restrict__ WallT, u16* __restrict__ WoT) {
    int i = blockIdx.x * 256 + threadIdx.x;  // 1024*512 + 512*512 = 786432
    if (i < 524288) {
        int n = i >> 9, k = i & 511;
        float v;
        if (n < 256)      v = Wq[k * 256 + n] * 0.18033688011f;
        else if (n < 512) v = Wk[k * 256 + (n - 256)];
        else              v = Wv[k * 512 + (n - 512)];
        WallT[i] = f2bf(v);
    } else {
        int j = i - 524288;
        int n = j >> 9, k = j & 511;
        WoT[j] = f2bf(Wo[k * 512 + n]);
    }
}

// ---------------- GEMM: C[M][N] = A[M][K] * BT[N][K]^T, 64x64 tile --------
// R4-proven staging: short8 VALU loads into padded (stride-72) LDS.
// mode 1: fp32 plain store (ldc). mode 2: QKV routing by nbase:
//   nbase<256 -> Qp packed; <512 -> Kp packed; else Vp packed.
// Qp: ((((b*4+h)*128+qs)*2+ki)*64+lane)*8+j <-> Q[b*2048+qs*16+lq][h*64+ki*32+quad*8+j]
// Kp: ((((((b*4+h)*32+kt)*2+half)*2+nj)*2+ki)*64+lane)*8+j
// Vp: ((((((b*4+h)*32+kt)*2+half)*4+ni)*2+w)*64+lane)*8+j
__global__ __launch_bounds__(256) void gemm_kernel(
    const u16* __restrict__ A, const u16* __restrict__ BT,
    float* __restrict__ Cf, u16* __restrict__ Qp, u16* __restrict__ Kp,
    u16* __restrict__ Vp, int Kdim, int ldc, int mode) {
    __shared__ u16 Asl[64 * 72];
    __shared__ u16 Bsl[64 * 72];
    const int tid = threadIdx.x;
    const int mbase = blockIdx.y * 64;
    const int nbase = blockIdx.x * 64;
    const int wave = tid >> 6, lane = tid & 63;
    const int wm = wave >> 1, wn = wave & 1;
    const int lq = lane & 15, quad = lane >> 4;

    const floatx4 z4 = {0.f, 0.f, 0.f, 0.f};
    floatx4 acc[2][2];
#pragma unroll
    for (int i = 0; i < 2; i++)
#pragma unroll
        for (int j = 0; j < 2; j++) acc[i][j] = z4;

    const int nk = Kdim >> 6;
    for (int kk = 0; kk < nk; kk++) {
        const int kb = kk << 6;
        if (kk) __syncthreads();
        {   // stage 64x64 of A and BT (8KB each): 2 short8 per thread each
            int row = tid >> 3, cc = (tid & 7) << 3;
            *(short8*)&Asl[row * 72 + cc] =
                *(const short8*)&A[(size_t)(mbase + row) * Kdim + kb + cc];
            *(short8*)&Bsl[row * 72 + cc] =
                *(const short8*)&BT[(size_t)(nbase + row) * Kdim + kb + cc];
            int c2 = 256 + tid;
            int row2 = c2 >> 3, cc2 = (c2 & 7) << 3;
            *(short8*)&Asl[row2 * 72 + cc2] =
                *(const short8*)&A[(size_t)(mbase + row2) * Kdim + kb + cc2];
            *(short8*)&Bsl[row2 * 72 + cc2] =
                *(const short8*)&BT[(size_t)(nbase + row2) * Kdim + kb + cc2];
        }
        __syncthreads();
#pragma unroll
        for (int ki = 0; ki < 2; ki++) {
            short8 af[2], bf[2];
#pragma unroll
            for (int mi = 0; mi < 2; mi++)
                af[mi] = *(const short8*)&Asl[(wm * 32 + mi * 16 + lq) * 72 + ki * 32 + quad * 8];
#pragma unroll
            for (int ni = 0; ni < 2; ni++)
                bf[ni] = *(const short8*)&Bsl[(wn * 32 + ni * 16 + lq) * 72 + ki * 32 + quad * 8];
#pragma unroll
            for (int mi = 0; mi < 2; mi++)
#pragma unroll
                for (int ni = 0; ni < 2; ni++)
                    acc[mi][ni] = MFMA16(af[mi], bf[ni], acc[mi][ni]);
        }
    }
    // epilogue: C/D layout col=lane&15, row=quad*4+reg (verified m89/m91)
    if (mode == 1) {
#pragma unroll
        for (int mi = 0; mi < 2; mi++)
#pragma unroll
            for (int ni = 0; ni < 2; ni++)
#pragma unroll
                for (int r = 0; r < 4; r++)
                    Cf[(size_t)(mbase + wm * 32 + mi * 16 + quad * 4 + r) * ldc +
                       (nbase + wn * 32 + ni * 16 + lq)] = acc[mi][ni][r];
    } else if (nbase < 256) {  // Q-packed
#pragma unroll
        for (int mi = 0; mi < 2; mi++)
#pragma unroll
            for (int ni = 0; ni < 2; ni++) {
                int col = nbase + wn * 32 + ni * 16 + lq;        // [0,256)
                int hq = col >> 6, dkc = col & 63;
                int ki = dkc >> 5, qd = (dkc >> 3) & 3, jq = dkc & 7;
#pragma unroll
                for (int r = 0; r < 4; r++) {
                    int row = mbase + wm * 32 + mi * 16 + quad * 4 + r;
                    int b = row >> 11, q = row & 2047;
                    int qs = q >> 4, lqq = q & 15;
                    Qp[((size_t)((((b * 4 + hq) * 128 + qs) * 2 + ki) * 64 +
                                 (qd * 16 + lqq)) << 3) + jq] = f2bf(acc[mi][ni][r]);
                }
            }
    } else if (nbase < 512) {  // K-packed
#pragma unroll
        for (int mi = 0; mi < 2; mi++)
#pragma unroll
            for (int ni = 0; ni < 2; ni++) {
                int colk = nbase + wn * 32 + ni * 16 + lq - 256;  // [0,256)
                int h = colk >> 6, dkc = colk & 63;
                int ki = dkc >> 5, quadk = (dkc >> 3) & 3, j = dkc & 7;
#pragma unroll
                for (int r = 0; r < 4; r++) {
                    int row = mbase + wm * 32 + mi * 16 + quad * 4 + r;
                    int b = row >> 11, key = row & 2047;
                    int kt = key >> 6, r6 = key & 63;
                    int half = r6 >> 5, r5 = r6 & 31;
                    int lqk = r5 >> 1, nj = r5 & 1;
                    Kp[((size_t)((((((b * 4 + h) * 32 + kt) * 2 + half) * 2 + nj)
                                  * 2 + ki) * 64 + (quadk * 16 + lqk)) << 3) + j] =
                        f2bf(acc[mi][ni][r]);
                }
            }
    } else {  // V-packed: row=token -> (b,key), col-512 = dv
#pragma unroll
        for (int mi = 0; mi < 2; mi++)
#pragma unroll
            for (int ni = 0; ni < 2; ni++) {
                int dv = nbase + wn * 32 + ni * 16 + lq - 512;    // [0,512)
                int h = dv >> 7, r7 = dv & 127;
                int half = r7 >> 6, r6v = r7 & 63;
                int niv = r6v >> 4, lqv = r6v & 15;
#pragma unroll
                for (int r = 0; r < 4; r++) {
                    int row = mbase + wm * 32 + mi * 16 + quad * 4 + r;
                    int b = row >> 11, key = row & 2047;
                    int kt = key >> 6, r6 = key & 63;
                    int w = r6 >> 5, r5 = r6 & 31;
                    int quadv = r5 >> 3, jv = r5 & 7;
                    Vp[((size_t)((((((b * 4 + h) * 32 + kt) * 2 + half) * 4 + niv)
                                  * 2 + w) * 64 + (quadv * 16 + lqv)) << 3) + jv] =
                        f2bf(acc[mi][ni][r]);
                }
            }
    }
}

// ---------------- fused attention: shared-P, one barrier per kt ----------
// Grid: 1024 WGs = h(bx&3) x chunk((bx>>2)&3) x qtile(bx>>4, 64 of 32 rows).
// Block: 4 waves; wave = (mi = q-sub16, t = wave>>1). S phase: wave computes
// S+softmax for keys [t*32,+32); P -> per-mi double-buffered LDS; one
// __syncthreads; PV phase: full 64-key P, dv-half t.
// Epilogue: plain bf16 stores into this chunk's private partial buffer.
__global__ __launch_bounds__(256) void attn_kernel(const u16* __restrict__ Qp,
                                                   const u16* __restrict__ Kp,
                                                   const u16* __restrict__ Vp,
                                                   u16* __restrict__ Pp) {
    __shared__ u16 pl[2 * 2 * 4 * 16 * 72];  // [buf][mi][b][q16][k72], 36.9KB
    const int bx = blockIdx.x;
    const int h = bx & 3;
    const int ck = (bx >> 2) & 3;
    const int qt = bx >> 4;
    const int tid = threadIdx.x;
    const int wave = tid >> 6, lane = tid & 63;
    const int mi = wave & 1, half = wave >> 1;  // S key-half / PV dv-half
    const int lq = lane & 15, quad = lane >> 4;
    const int q0 = qt * 32 + mi * 16;

    // Q a-frags (fragment-packed, coalesced): A[m=lane&15][k=quad*8+j]
    short8 aq[4][2];
#pragma unroll
    for (int b = 0; b < 4; b++)
#pragma unroll
        for (int ki = 0; ki < 2; ki++)
            aq[b][ki] = *(const short8*)&Qp[
                ((size_t)((((b * 4 + h) * 128 + (qt * 2 + mi)) * 2 + ki) * 64 + lane) << 3)];

    const floatx4 z4 = {0.f, 0.f, 0.f, 0.f};
    floatx4 oacc[4][4];
#pragma unroll
    for (int b = 0; b < 4; b++)
#pragma unroll
        for (int ni = 0; ni < 4; ni++) oacc[b][ni] = z4;

    for (int kt = ck * 8; kt < ck * 8 + 8; kt++) {
        u16* plb = &pl[((kt & 1) * 2 + mi) * (4 * 16 * 72)];
        // ---- S (log2 domain) for this wave's 32 keys, all 4 batches ----
        floatx4 s[4][2];
#pragma unroll
        for (int b = 0; b < 4; b++) {
            const u16* kb = Kp +
                ((size_t)((((b * 4 + h) * 32 + kt) * 2 + half) * 2) << 10) +
                lane * 8;
#pragma unroll
            for (int nj = 0; nj < 2; nj++) {
                s[b][nj] = z4;
#pragma unroll
                for (int ki = 0; ki < 2; ki++)
                    s[b][nj] = MFMA16(aq[b][ki],
                                      *(const short8*)(kb + (nj * 2 + ki) * 512),
                                      s[b][nj]);
            }
        }
        // ---- softmax over batch: e = 2^S (no max-sub; |S| small) ----
        // lane holds S[q=quad*4+r][key = half*32 + 2*lq + nj]
#pragma unroll
        for (int r = 0; r < 4; r++) {
            float e0a = ex2(s[0][0][r]), e0b = ex2(s[0][1][r]);
            float e1a = ex2(s[1][0][r]), e1b = ex2(s[1][1][r]);
            float e2a = ex2(s[2][0][r]), e2b = ex2(s[2][1][r]);
            float e3a = ex2(s[3][0][r]), e3b = ex2(s[3][1][r]);
            float ia = __builtin_amdgcn_rcpf(e0a + e1a + e2a + e3a);
            float ib = __builtin_amdgcn_rcpf(e0b + e1b + e2b + e3b);
            int q = quad * 4 + r, col = half * 32 + 2 * lq;
            *(u32*)&plb[(0 * 16 + q) * 72 + col] = pk2bf(e0a * ia, e0b * ib);
            *(u32*)&plb[(1 * 16 + q) * 72 + col] = pk2bf(e1a * ia, e1b * ib);
            *(u32*)&plb[(2 * 16 + q) * 72 + col] = pk2bf(e2a * ia, e2b * ib);
            *(u32*)&plb[(3 * 16 + q) * 72 + col] = pk2bf(e3a * ia, e3b * ib);
        }
        __syncthreads();  // P complete for both key-halves of this buffer
        // ---- O += P V : full 64 keys, this wave's dv-half ----
#pragma unroll
        for (int b = 0; b < 4; b++) {
            short8 ap0 = *(const short8*)&plb[(b * 16 + lq) * 72 + quad * 8];
            short8 ap1 = *(const short8*)&plb[(b * 16 + lq) * 72 + 32 + quad * 8];
            const u16* vb = Vp +
                ((size_t)((((b * 4 + h) * 32 + kt) * 2 + half) * 8) << 9) +
                lane * 8;
#pragma unroll
            for (int ni = 0; ni < 4; ni++) {
                oacc[b][ni] = MFMA16(ap0, *(const short8*)(vb + (ni * 2 + 0) * 512),
                                     oacc[b][ni]);
                oacc[b][ni] = MFMA16(ap1, *(const short8*)(vb + (ni * 2 + 1) * 512),
                                     oacc[b][ni]);
            }
        }
        // next iteration writes the other buffer -> no second barrier
    }
    // ---- epilogue: plain bf16 stores to this chunk's partial buffer ----
    u16* Pc = Pp + (size_t)ck * (8192 * 512);
#pragma unroll
    for (int b = 0; b < 4; b++)
#pragma unroll
        for (int ni = 0; ni < 4; ni++)
#pragma unroll
            for (int r = 0; r < 4; r++)
                Pc[(size_t)(b * 2048 + q0 + quad * 4 + r) * 512 +
                   h * 128 + half * 64 + ni * 16 + lq] = f2bf(oacc[b][ni][r]);
}

// ---------------- reduce 4 bf16 partials in place (P0 += P1+P2+P3) --------
__global__ __launch_bounds__(256) void reduce4_kernel(u16* __restrict__ P) {
    const size_t S = (size_t)8192 * 512;
    size_t i = ((size_t)blockIdx.x * 256 + threadIdx.x) * 8;  // 2048 blocks
    short8 a = *(short8*)&P[i];
    short8 b = *(short8*)&P[i + S];
    short8 c = *(short8*)&P[i + 2 * S];
    short8 d = *(short8*)&P[i + 3 * S];
    short8 o;
#pragma unroll
    for (int j = 0; j < 8; j++) {
        float s = bf2f((u16)a[j]) + bf2f((u16)b[j]) +
                  bf2f((u16)c[j]) + bf2f((u16)d[j]);
        o[j] = (short)f2bf(s);
    }
    *(short8*)&P[i] = o;
}

extern "C" void kernel_launch(void* const* d_in, const int* in_sizes, int n_in,
                              void* d_out, int out_size, void* d_ws, size_t ws_size,
                              hipStream_t stream) {
    const float* x  = (const float*)d_in[0];
    const float* Wq = (const float*)d_in[1];
    const float* Wk = (const float*)d_in[2];
    const float* Wv = (const float*)d_in[3];
    const float* Wo = (const float*)d_in[4];
    float* out = (float*)d_out;

    // Workspace map (48.5 MB). Pp[0..4) partials occupy [0, 32MB); Xb (8MB)
    // and WallT (1MB) are OVERLAID at the start of that region -- both dead
    // before attn writes partials. P0 doubles as AO after reduce4.
    char* ws = (char*)d_ws;
    u16* Pp    = (u16*)ws;                                   // 4 x 8MB bf16
    u16* Xb    = (u16*)ws;                                   // overlay [0,8MB)
    u16* WallT = (u16*)(ws + (size_t)8 * 1024 * 1024);       // overlay [8,9MB)
    char* tail = ws + (size_t)32 * 1024 * 1024;
    u16* WoT   = (u16*)tail; tail += (size_t)512 * 512 * 2;  // 0.5MB
    u16* Qp    = (u16*)tail; tail += (size_t)8192 * 256 * 2; // 4MB
    u16* Kp    = (u16*)tail; tail += (size_t)8192 * 256 * 2; // 4MB
    u16* Vp    = (u16*)tail; tail += (size_t)8192 * 512 * 2; // 8MB

    cast_x_kernel<<<4096, 256, 0, stream>>>(x, Xb);
    prep_w_kernel<<<3072, 256, 0, stream>>>(Wq, Wk, Wv, Wo, WallT, WoT);
    // QKV = X @ [Wq|Wk|Wv] : [8192,1024] -> Qp/Kp/Vp packed
    gemm_kernel<<<dim3(16, 128), 256, 0, stream>>>(Xb, WallT, nullptr,
                                                   Qp, Kp, Vp, 512, 0, 2);
    attn_kernel<<<1024, 256, 0, stream>>>(Qp, Kp, Vp, Pp);
    reduce4_kernel<<<2048, 256, 0, stream>>>(Pp);
    // out = AO(=P0) @ Wo : fp32
    gemm_kernel<<<dim3(8, 128), 256, 0, stream>>>(Pp, WoT, out,
                                                  nullptr, nullptr, nullptr,
                                                  512, 512, 1);
}

// Round 7
// 186.756 us; speedup vs baseline: 1.7693x; 1.7693x over previous
//
#include <hip/hip_runtime.h>
#include <hip/hip_bf16.h>

// B=4, N=2048, D_MODEL=512, H=4, DK=64, DV=128. fp32 in/out, bf16 MFMA.
// Softmax over BATCH axis (4 values) -> in-register per lane.
// R7: (1) attn q-tile 64, block 512 (8 waves = 4 mi x 2 half): halves the
// distinct K/V L2 traffic, mi-waves share K/V lines via L1. P in unpadded
// stride-64 LDS with XOR-chunk swizzle (col ^= (row&7)*8) -> 8 regions =
// exactly 64KB, 2 WGs/CU. (2) GEMMs: R1-proven 128x128 tile + packed
// epilogues (QKV grid 512, out grid 256).

typedef __attribute__((ext_vector_type(8))) short short8;   // 8 x bf16
typedef __attribute__((ext_vector_type(4))) float floatx4;  // MFMA 16x16 acc
typedef unsigned short u16;
typedef unsigned int u32;

#define MFMA16(a, b, c) __builtin_amdgcn_mfma_f32_16x16x32_bf16((a), (b), (c), 0, 0, 0)

__device__ __forceinline__ u16 f2bf(float f) {
    union { float f; unsigned u; } v; v.f = f;
    unsigned r = v.u + 0x7fffu + ((v.u >> 16) & 1u);  // RNE
    return (u16)(r >> 16);
}

__device__ __forceinline__ float bf2f(u16 b) {
    union { unsigned u; float f; } v; v.u = ((u32)b) << 16;
    return v.f;
}

__device__ __forceinline__ u32 pk2bf(float a, float b) {
#if __has_builtin(__builtin_amdgcn_cvt_pk_bf16_f32)
    typedef __attribute__((ext_vector_type(2))) __bf16 bf16x2;
    union { bf16x2 v; u32 u; } c;
    c.v = __builtin_amdgcn_cvt_pk_bf16_f32(a, b);
    return c.u;
#else
    return (u32)f2bf(a) | ((u32)f2bf(b) << 16);
#endif
}

__device__ __forceinline__ float ex2(float x) {
#if __has_builtin(__builtin_amdgcn_exp2f)
    return __builtin_amdgcn_exp2f(x);
#else
    return exp2f(x);
#endif
}

// ---------------- cast fp32 -> bf16 (X) ----------------
__global__ __launch_bounds__(256) void cast_x_kernel(const float* __restrict__ x,
                                                     u16* __restrict__ xb) {
    int i = blockIdx.x * 256 + threadIdx.x;  // 1,048,576 float4 groups exactly
    float4 v = ((const float4*)x)[i];
    ushort4 o;
    o.x = f2bf(v.x); o.y = f2bf(v.y); o.z = f2bf(v.z); o.w = f2bf(v.w);
    ((ushort4*)xb)[i] = o;
}

// ---- weights: fp32 [K][N] -> bf16 transposed [N][K]; [Wq|Wk|Wv] fused ----
// Q columns pre-scaled by 0.125*log2(e) so S arrives in log2 domain.
__global__ __launch_bounds__(256) void prep_w_kernel(
    const float* __restrict__ Wq, const float* __restrict__ Wk,
    const float* __restrict__ Wv, const float* __restrict__ Wo,
    u16* __restrict__ WallT, u16* __restrict__ WoT) {
    int i = blockIdx.x * 256 + threadIdx.x;  // 1024*512 + 512*512 = 786432
    if (i < 524288) {
        int n = i >> 9, k = i & 511;
        float v;
        if (n < 256)      v = Wq[k * 256 + n] * 0.18033688011f;
        else if (n < 512) v = Wk[k * 256 + (n - 256)];
        else              v = Wv[k * 512 + (n - 512)];
        WallT[i] = f2bf(v);
    } else {
        int j = i - 524288;
        int n = j >> 9, k = j & 511;
        WoT[j] = f2bf(Wo[k * 512 + n]);
    }
}

// ------- GEMM: C[M][N] = A[M][K] * BT[N][K]^T, 128x128 tile (R1-proven) ----
// 4 waves 2x2, each wave 64x64 (4x4 c-frags). BK=64, LDS rows padded to 72.
// mode 1: fp32 plain store (ldc). mode 2: QKV routing by nbase:
//   nbase<256 -> Qp packed; <512 -> Kp packed; else Vp packed.
// Qp: ((((b*4+h)*128+qs)*2+ki)*64+lane)*8+j
// Kp: ((((((b*4+h)*32+kt)*2+half)*2+nj)*2+ki)*64+lane)*8+j
// Vp: ((((((b*4+h)*32+kt)*2+half)*4+ni)*2+w)*64+lane)*8+j
__global__ __launch_bounds__(256) void gemm_kernel(
    const u16* __restrict__ A, const u16* __restrict__ BT,
    float* __restrict__ Cf, u16* __restrict__ Qp, u16* __restrict__ Kp,
    u16* __restrict__ Vp, int Kdim, int ldc, int mode) {
    __shared__ u16 Asl[128 * 72];
    __shared__ u16 Bsl[128 * 72];
    const int tid = threadIdx.x;
    const int mbase = blockIdx.y * 128;
    const int nbase = blockIdx.x * 128;
    const int wave = tid >> 6, lane = tid & 63;
    const int wm = wave >> 1, wn = wave & 1;
    const int lq = lane & 15, quad = lane >> 4;

    const floatx4 z4 = {0.f, 0.f, 0.f, 0.f};
    floatx4 acc[4][4];
#pragma unroll
    for (int i = 0; i < 4; i++)
#pragma unroll
        for (int j = 0; j < 4; j++) acc[i][j] = z4;

    const int nk = Kdim >> 6;
    for (int kk = 0; kk < nk; kk++) {
        const int kb = kk << 6;
        if (kk) __syncthreads();
#pragma unroll
        for (int i = 0; i < 4; i++) {  // stage 128x64 of A and BT (16KB each)
            int c = i * 256 + tid;
            int row = c >> 3, cc = (c & 7) << 3;
            *(short8*)&Asl[row * 72 + cc] =
                *(const short8*)&A[(size_t)(mbase + row) * Kdim + kb + cc];
            *(short8*)&Bsl[row * 72 + cc] =
                *(const short8*)&BT[(size_t)(nbase + row) * Kdim + kb + cc];
        }
        __syncthreads();
#pragma unroll
        for (int ki = 0; ki < 2; ki++) {
            short8 af[4], bf[4];
#pragma unroll
            for (int mi = 0; mi < 4; mi++)
                af[mi] = *(const short8*)&Asl[(wm * 64 + mi * 16 + lq) * 72 + ki * 32 + quad * 8];
#pragma unroll
            for (int ni = 0; ni < 4; ni++)
                bf[ni] = *(const short8*)&Bsl[(wn * 64 + ni * 16 + lq) * 72 + ki * 32 + quad * 8];
#pragma unroll
            for (int mi = 0; mi < 4; mi++)
#pragma unroll
                for (int ni = 0; ni < 4; ni++)
                    acc[mi][ni] = MFMA16(af[mi], bf[ni], acc[mi][ni]);
        }
    }
    // epilogue: C/D layout col=lane&15, row=quad*4+reg (verified m89/m91)
    if (mode == 1) {
#pragma unroll
        for (int mi = 0; mi < 4; mi++)
#pragma unroll
            for (int ni = 0; ni < 4; ni++)
#pragma unroll
                for (int r = 0; r < 4; r++)
                    Cf[(size_t)(mbase + wm * 64 + mi * 16 + quad * 4 + r) * ldc +
                       (nbase + wn * 64 + ni * 16 + lq)] = acc[mi][ni][r];
    } else if (nbase < 256) {  // Q-packed
#pragma unroll
        for (int mi = 0; mi < 4; mi++)
#pragma unroll
            for (int ni = 0; ni < 4; ni++) {
                int col = nbase + wn * 64 + ni * 16 + lq;        // [0,256)
                int hq = col >> 6, dkc = col & 63;
                int ki = dkc >> 5, qd = (dkc >> 3) & 3, jq = dkc & 7;
#pragma unroll
                for (int r = 0; r < 4; r++) {
                    int row = mbase + wm * 64 + mi * 16 + quad * 4 + r;
                    int b = row >> 11, q = row & 2047;
                    int qs = q >> 4, lqq = q & 15;
                    Qp[((size_t)((((b * 4 + hq) * 128 + qs) * 2 + ki) * 64 +
                                 (qd * 16 + lqq)) << 3) + jq] = f2bf(acc[mi][ni][r]);
                }
            }
    } else if (nbase < 512) {  // K-packed
#pragma unroll
        for (int mi = 0; mi < 4; mi++)
#pragma unroll
            for (int ni = 0; ni < 4; ni++) {
                int colk = nbase + wn * 64 + ni * 16 + lq - 256;  // [0,256)
                int h = colk >> 6, dkc = colk & 63;
                int ki = dkc >> 5, quadk = (dkc >> 3) & 3, j = dkc & 7;
#pragma unroll
                for (int r = 0; r < 4; r++) {
                    int row = mbase + wm * 64 + mi * 16 + quad * 4 + r;
                    int b = row >> 11, key = row & 2047;
                    int kt = key >> 6, r6 = key & 63;
                    int half = r6 >> 5, r5 = r6 & 31;
                    int lqk = r5 >> 1, nj = r5 & 1;
                    Kp[((size_t)((((((b * 4 + h) * 32 + kt) * 2 + half) * 2 + nj)
                                  * 2 + ki) * 64 + (quadk * 16 + lqk)) << 3) + j] =
                        f2bf(acc[mi][ni][r]);
                }
            }
    } else {  // V-packed: row=token -> (b,key), col-512 = dv
#pragma unroll
        for (int mi = 0; mi < 4; mi++)
#pragma unroll
            for (int ni = 0; ni < 4; ni++) {
                int dv = nbase + wn * 64 + ni * 16 + lq - 512;    // [0,512)
                int h = dv >> 7, r7 = dv & 127;
                int half = r7 >> 6, r6v = r7 & 63;
                int niv = r6v >> 4, lqv = r6v & 15;
#pragma unroll
                for (int r = 0; r < 4; r++) {
                    int row = mbase + wm * 64 + mi * 16 + quad * 4 + r;
                    int b = row >> 11, key = row & 2047;
                    int kt = key >> 6, r6 = key & 63;
                    int w = r6 >> 5, r5 = r6 & 31;
                    int quadv = r5 >> 3, jv = r5 & 7;
                    Vp[((size_t)((((((b * 4 + h) * 32 + kt) * 2 + half) * 4 + niv)
                                  * 2 + w) * 64 + (quadv * 16 + lqv)) << 3) + jv] =
                        f2bf(acc[mi][ni][r]);
                }
            }
    }
}

// ---------------- fused attention: q64-tile, 8 waves, shared-P -----------
// Grid: 512 WGs = h(bx&3) x chunk((bx>>2)&3) x qtile(bx>>4, 32 of 64 rows).
// Block: 8 waves; wave = (mi = wave&3 -> q-sub16, half = wave>>2).
// Per kt: wave computes S+softmax for its mi x its half's 32 keys (no dup);
// P -> per-mi double-buffered LDS (XOR-swizzled, stride 64); 1 barrier;
// PV: full 64-key P, dv-half `half`. The 4 mi-waves read identical K/V
// lines barrier-aligned -> L1 dedup.
// Swizzle: element (row q, col c) stored at col c ^ ((q&7)*8); writes and
// reads use the same mask (row = q = lq on read) -> round-trip exact.
__global__ __launch_bounds__(512) void attn_kernel(const u16* __restrict__ Qp,
                                                   const u16* __restrict__ Kp,
                                                   const u16* __restrict__ Vp,
                                                   u16* __restrict__ Pp) {
    __shared__ u16 pl[2 * 4 * 4096];  // [buf][mi][b*16+q][64], 64 KB exactly
    const int bx = blockIdx.x;
    const int h = bx & 3;
    const int ck = (bx >> 2) & 3;
    const int qt = bx >> 4;                     // [0,32)
    const int tid = threadIdx.x;
    const int wave = tid >> 6, lane = tid & 63;
    const int mi = wave & 3, half = wave >> 2;  // S key-half / PV dv-half
    const int lq = lane & 15, quad = lane >> 4;
    const int q0 = qt * 64 + mi * 16;
    const int qs = qt * 4 + mi;                 // q0 >> 4

    // Q a-frags (fragment-packed, coalesced): A[m=lane&15][k=quad*8+j]
    short8 aq[4][2];
#pragma unroll
    for (int b = 0; b < 4; b++)
#pragma unroll
        for (int ki = 0; ki < 2; ki++)
            aq[b][ki] = *(const short8*)&Qp[
                ((size_t)((((b * 4 + h) * 128 + qs) * 2 + ki) * 64 + lane) << 3)];

    const floatx4 z4 = {0.f, 0.f, 0.f, 0.f};
    floatx4 oacc[4][4];
#pragma unroll
    for (int b = 0; b < 4; b++)
#pragma unroll
        for (int ni = 0; ni < 4; ni++) oacc[b][ni] = z4;

    for (int kt = ck * 8; kt < ck * 8 + 8; kt++) {
        u16* plb = &pl[((kt & 1) * 4 + mi) * 4096];
        // ---- S (log2 domain) for this wave's 32 keys, all 4 batches ----
        floatx4 s[4][2];
#pragma unroll
        for (int b = 0; b < 4; b++) {
            const u16* kb = Kp +
                ((size_t)((((b * 4 + h) * 32 + kt) * 2 + half) * 2) << 10) +
                lane * 8;
#pragma unroll
            for (int nj = 0; nj < 2; nj++) {
                s[b][nj] = z4;
#pragma unroll
                for (int ki = 0; ki < 2; ki++)
                    s[b][nj] = MFMA16(aq[b][ki],
                                      *(const short8*)(kb + (nj * 2 + ki) * 512),
                                      s[b][nj]);
            }
        }
        // ---- softmax over batch: e = 2^S (no max-sub; |S| small) ----
        // lane holds S[q=quad*4+r][key = half*32 + 2*lq + nj]
#pragma unroll
        for (int r = 0; r < 4; r++) {
            float e0a = ex2(s[0][0][r]), e0b = ex2(s[0][1][r]);
            float e1a = ex2(s[1][0][r]), e1b = ex2(s[1][1][r]);
            float e2a = ex2(s[2][0][r]), e2b = ex2(s[2][1][r]);
            float e3a = ex2(s[3][0][r]), e3b = ex2(s[3][1][r]);
            float ia = __builtin_amdgcn_rcpf(e0a + e1a + e2a + e3a);
            float ib = __builtin_amdgcn_rcpf(e0b + e1b + e2b + e3b);
            int q = quad * 4 + r;
            int col = (half * 32 + 2 * lq) ^ ((q & 7) * 8);  // XOR swizzle
            *(u32*)&plb[(0 * 16 + q) * 64 + col] = pk2bf(e0a * ia, e0b * ib);
            *(u32*)&plb[(1 * 16 + q) * 64 + col] = pk2bf(e1a * ia, e1b * ib);
            *(u32*)&plb[(2 * 16 + q) * 64 + col] = pk2bf(e2a * ia, e2b * ib);
            *(u32*)&plb[(3 * 16 + q) * 64 + col] = pk2bf(e3a * ia, e3b * ib);
        }
        __syncthreads();  // P complete for both key-halves of this buffer
        // ---- O += P V : full 64 keys, this wave's dv-half ----
        const int sw = (lq & 7) * 8;
#pragma unroll
        for (int b = 0; b < 4; b++) {
            short8 ap0 = *(const short8*)&plb[(b * 16 + lq) * 64 + ((quad * 8) ^ sw)];
            short8 ap1 = *(const short8*)&plb[(b * 16 + lq) * 64 + ((32 + quad * 8) ^ sw)];
            const u16* vb = Vp +
                ((size_t)((((b * 4 + h) * 32 + kt) * 2 + half) * 8) << 9) +
                lane * 8;
#pragma unroll
            for (int ni = 0; ni < 4; ni++) {
                oacc[b][ni] = MFMA16(ap0, *(const short8*)(vb + (ni * 2 + 0) * 512),
                                     oacc[b][ni]);
                oacc[b][ni] = MFMA16(ap1, *(const short8*)(vb + (ni * 2 + 1) * 512),
                                     oacc[b][ni]);
            }
        }
        // next iteration writes the other buffer -> no second barrier
    }
    // ---- epilogue: plain bf16 stores to this chunk's partial buffer ----
    u16* Pc = Pp + (size_t)ck * (8192 * 512);
#pragma unroll
    for (int b = 0; b < 4; b++)
#pragma unroll
        for (int ni = 0; ni < 4; ni++)
#pragma unroll
            for (int r = 0; r < 4; r++)
                Pc[(size_t)(b * 2048 + q0 + quad * 4 + r) * 512 +
                   h * 128 + half * 64 + ni * 16 + lq] = f2bf(oacc[b][ni][r]);
}

// ---------------- reduce 4 bf16 partials in place (P0 += P1+P2+P3) --------
__global__ __launch_bounds__(256) void reduce4_kernel(u16* __restrict__ P) {
    const size_t S = (size_t)8192 * 512;
    size_t i = ((size_t)blockIdx.x * 256 + threadIdx.x) * 8;  // 2048 blocks
    short8 a = *(short8*)&P[i];
    short8 b = *(short8*)&P[i + S];
    short8 c = *(short8*)&P[i + 2 * S];
    short8 d = *(short8*)&P[i + 3 * S];
    short8 o;
#pragma unroll
    for (int j = 0; j < 8; j++) {
        float s = bf2f((u16)a[j]) + bf2f((u16)b[j]) +
                  bf2f((u16)c[j]) + bf2f((u16)d[j]);
        o[j] = (short)f2bf(s);
    }
    *(short8*)&P[i] = o;
}

extern "C" void kernel_launch(void* const* d_in, const int* in_sizes, int n_in,
                              void* d_out, int out_size, void* d_ws, size_t ws_size,
                              hipStream_t stream) {
    const float* x  = (const float*)d_in[0];
    const float* Wq = (const float*)d_in[1];
    const float* Wk = (const float*)d_in[2];
    const float* Wv = (const float*)d_in[3];
    const float* Wo = (const float*)d_in[4];
    float* out = (float*)d_out;

    // Workspace map (48.5 MB). Pp[0..4) partials occupy [0, 32MB); Xb (8MB)
    // and WallT (1MB) are OVERLAID at the start of that region -- both dead
    // before attn writes partials. P0 doubles as AO after reduce4.
    char* ws = (char*)d_ws;
    u16* Pp    = (u16*)ws;                                   // 4 x 8MB bf16
    u16* Xb    = (u16*)ws;                                   // overlay [0,8MB)
    u16* WallT = (u16*)(ws + (size_t)8 * 1024 * 1024);       // overlay [8,9MB)
    char* tail = ws + (size_t)32 * 1024 * 1024;
    u16* WoT   = (u16*)tail; tail += (size_t)512 * 512 * 2;  // 0.5MB
    u16* Qp    = (u16*)tail; tail += (size_t)8192 * 256 * 2; // 4MB
    u16* Kp    = (u16*)tail; tail += (size_t)8192 * 256 * 2; // 4MB
    u16* Vp    = (u16*)tail; tail += (size_t)8192 * 512 * 2; // 8MB

    cast_x_kernel<<<4096, 256, 0, stream>>>(x, Xb);
    prep_w_kernel<<<3072, 256, 0, stream>>>(Wq, Wk, Wv, Wo, WallT, WoT);
    // QKV = X @ [Wq|Wk|Wv] : [8192,1024] -> Qp/Kp/Vp packed (grid 512, 2/CU)
    gemm_kernel<<<dim3(8, 64), 256, 0, stream>>>(Xb, WallT, nullptr,
                                                 Qp, Kp, Vp, 512, 0, 2);
    attn_kernel<<<512, 512, 0, stream>>>(Qp, Kp, Vp, Pp);
    reduce4_kernel<<<2048, 256, 0, stream>>>(Pp);
    // out = AO(=P0) @ Wo : fp32
    gemm_kernel<<<dim3(4, 64), 256, 0, stream>>>(Pp, WoT, out,
                                                 nullptr, nullptr, nullptr,
                                                 512, 512, 1);
}